// Round 8
// baseline (685.949 us; speedup 1.0000x reference)
//
#include <hip/hip_runtime.h>

#define NNODES 100000
#define NEDGES 1600000
#define FIN 128
#define FH 64
#define FOUT 32
#define NGRAPH 128
#define EPSV 1e-5f

#define SCAN_BT 256
#define NBLK ((NNODES + SCAN_BT - 1) / SCAN_BT)  // 391

typedef unsigned short ushort_t;

// ---- bf16 helpers (RNE) ----
__device__ inline unsigned f2bf(float f) {
  union { float f; unsigned u; } x;
  x.f = f;
  return (x.u + 0x7fffu + ((x.u >> 16) & 1u)) >> 16;
}
__device__ inline float bflo(unsigned u) {
  union { unsigned u; float f; } x;
  x.u = u << 16;
  return x.f;
}
__device__ inline float bfhi(unsigned u) {
  union { unsigned u; float f; } x;
  x.u = u & 0xffff0000u;
  return x.f;
}

// ---------------- degree / normalization ----------------

__global__ void k_init_deg(float* __restrict__ deg) {
  int i = blockIdx.x * blockDim.x + threadIdx.x;
  if (i < NNODES) deg[i] = 1.0f;  // self-loop contributes 1
}

__global__ void k_deg_accum(const int* __restrict__ dst, float* __restrict__ deg) {
  int i = blockIdx.x * blockDim.x + threadIdx.x;
  if (i < NEDGES) atomicAdd(&deg[dst[i]], 1.0f);
}

__global__ void k_rsqrt(float* __restrict__ deg) {
  int i = blockIdx.x * blockDim.x + threadIdx.x;
  if (i < NNODES) deg[i] = rsqrtf(deg[i]);  // deg >= 1 always
}

// ---------------- CSR build: hierarchical exclusive scan of in-degrees ------

__global__ void k_blocksum(const float* __restrict__ deg, int* __restrict__ bsum) {
  __shared__ int ls[SCAN_BT];
  int b = blockIdx.x, t = threadIdx.x;
  int i = b * SCAN_BT + t;
  ls[t] = (i < NNODES) ? (int)deg[i] - 1 : 0;
  __syncthreads();
  for (int s = SCAN_BT / 2; s > 0; s >>= 1) {
    if (t < s) ls[t] += ls[t + s];
    __syncthreads();
  }
  if (t == 0) bsum[b] = ls[0];
}

__global__ void k_scan_bsums(const int* __restrict__ bsum, int* __restrict__ boff) {
  __shared__ int ls[512];
  int t = threadIdx.x;
  int v = (t < NBLK) ? bsum[t] : 0;
  ls[t] = v;
  __syncthreads();
  for (int s = 1; s < 512; s <<= 1) {
    int add = (t >= s) ? ls[t - s] : 0;
    __syncthreads();
    ls[t] += add;
    __syncthreads();
  }
  if (t < NBLK) boff[t] = ls[t] - v;  // exclusive
}

__global__ void k_scan_final(const float* __restrict__ deg, const int* __restrict__ boff,
                             int* __restrict__ off) {
  __shared__ int ls[SCAN_BT];
  int b = blockIdx.x, t = threadIdx.x;
  int i = b * SCAN_BT + t;
  int v = (i < NNODES) ? (int)deg[i] - 1 : 0;
  ls[t] = v;
  __syncthreads();
  for (int s = 1; s < SCAN_BT; s <<= 1) {
    int add = (t >= s) ? ls[t - s] : 0;
    __syncthreads();
    ls[t] += add;
    __syncthreads();
  }
  if (i < NNODES) off[i] = boff[b] + ls[t] - v;  // exclusive offset
  if (i == NNODES - 1) off[NNODES] = boff[b] + ls[t];
}

// XCD-partitioned fill: blocks of class (blockIdx&7) handle only dst in their
// 12500-node slice -> each csr line / cursor counter is owned by ONE XCD's L2.

__global__ void k_fill(const int* __restrict__ src, const int* __restrict__ dst,
                       const int* __restrict__ off, int* __restrict__ cursor,
                       int* __restrict__ csr) {
  const int SLICE = NNODES / 8;  // 12500
  int xcd = blockIdx.x & 7;
  int lo = xcd * SLICE, hi = lo + SLICE;
  int chunk = blockIdx.x >> 3;
  int nchunk = gridDim.x >> 3;
  for (int i = chunk * blockDim.x + threadIdx.x; i < NEDGES; i += nchunk * blockDim.x) {
    int d = dst[i];
    if (d >= lo && d < hi) {
      int p = atomicAdd(&cursor[d], 1);
      csr[off[d] + p] = src[i];
    }
  }
}

// ---------------- skinny GEMM: out[N x 64] = act(A[N x K]) @ W[K x 64] -------
// ONE WAVE PER ROW, one output feature per lane. A-row reads are wave-uniform
// (1 broadcast request); W reads are coalesced 256B lines and L1-resident
// (32KB, reused by every wave). 25000 blocks -> full occupancy, latency hidden
// by TLP. Two acc chains for ILP. Epilogue scales by dis[row], stores bf16.

template <int K, bool BN>
__global__ void k_gemm(const float* __restrict__ A, const float* __restrict__ W,
                       const float* __restrict__ sc, const float* __restrict__ sh,
                       const float* __restrict__ dis, ushort_t* __restrict__ out) {
  int lane = threadIdx.x & 63;
  int row = (blockIdx.x * blockDim.x + threadIdx.x) >> 6;
  if (row >= NNODES) return;
  const float* a = A + (long long)row * K;
  float acc0 = 0.0f, acc1 = 0.0f;
  for (int k = 0; k < K; k += 8) {
    float4 xa = *(const float4*)(a + k);
    float4 xb = *(const float4*)(a + k + 4);
    float w0 = W[(k + 0) * FH + lane];
    float w1 = W[(k + 1) * FH + lane];
    float w2 = W[(k + 2) * FH + lane];
    float w3 = W[(k + 3) * FH + lane];
    float w4 = W[(k + 4) * FH + lane];
    float w5 = W[(k + 5) * FH + lane];
    float w6 = W[(k + 6) * FH + lane];
    float w7 = W[(k + 7) * FH + lane];
    float x0 = xa.x, x1 = xa.y, x2 = xa.z, x3 = xa.w;
    float x4 = xb.x, x5 = xb.y, x6 = xb.z, x7 = xb.w;
    if (BN) {
      x0 = fmaxf(fmaf(x0, sc[k + 0], sh[k + 0]), 0.0f);
      x1 = fmaxf(fmaf(x1, sc[k + 1], sh[k + 1]), 0.0f);
      x2 = fmaxf(fmaf(x2, sc[k + 2], sh[k + 2]), 0.0f);
      x3 = fmaxf(fmaf(x3, sc[k + 3], sh[k + 3]), 0.0f);
      x4 = fmaxf(fmaf(x4, sc[k + 4], sh[k + 4]), 0.0f);
      x5 = fmaxf(fmaf(x5, sc[k + 5], sh[k + 5]), 0.0f);
      x6 = fmaxf(fmaf(x6, sc[k + 6], sh[k + 6]), 0.0f);
      x7 = fmaxf(fmaf(x7, sc[k + 7], sh[k + 7]), 0.0f);
    }
    acc0 = fmaf(x0, w0, acc0);
    acc1 = fmaf(x1, w1, acc1);
    acc0 = fmaf(x2, w2, acc0);
    acc1 = fmaf(x3, w3, acc1);
    acc0 = fmaf(x4, w4, acc0);
    acc1 = fmaf(x5, w5, acc1);
    acc0 = fmaf(x6, w6, acc0);
    acc1 = fmaf(x7, w7, acc1);
  }
  float r = (acc0 + acc1) * dis[row];
  out[(long long)row * FH + lane] = (ushort_t)f2bf(r);
}

// ---------------- aggregation: out[d] = dis[d] * (hs[d] + sum hs[csr]) ------
// hs is bf16 (128B rows). Wave = 4 groups x 16 lanes; each lane loads uint2
// (4 bf16 feats). 4 independent row chains per group per iteration (16
// edges/iter/wave). Uniform trip count, tails via clamp+select. fp32 accum.

__global__ void k_gather(const ushort_t* __restrict__ hs, const int* __restrict__ csr,
                         const int* __restrict__ off, const float* __restrict__ dis,
                         float* __restrict__ out, float* __restrict__ stats) {
  __shared__ float ls[2 * FH];
  int tid = threadIdx.x;
  if (tid < 2 * FH) ls[tid] = 0.0f;
  __syncthreads();
  int lane = tid & 63;
  int g = lane >> 4;  // neighbor group 0..3
  int i = lane & 15;  // feature-quad: features [4i, 4i+3]
  int wid = (blockIdx.x * blockDim.x + tid) >> 6;
  int nw = (gridDim.x * blockDim.x) >> 6;
  float s1x = 0, s1y = 0, s1z = 0, s1w = 0;
  float s2x = 0, s2y = 0, s2z = 0, s2w = 0;
  for (int d = wid; d < NNODES; d += nw) {
    int b = off[d], e = off[d + 1];
    uint2 su = *(const uint2*)(hs + (long long)d * FH + i * 4);
    float ax = (g == 0) ? bflo(su.x) : 0.0f;
    float ay = (g == 0) ? bfhi(su.x) : 0.0f;
    float az = (g == 0) ? bflo(su.y) : 0.0f;
    float aw = (g == 0) ? bfhi(su.y) : 0.0f;
    int niter = (e - b + 15) >> 4;  // wave-uniform
    int last = e - 1;
    int k0 = b + g;
    for (int j = 0; j < niter; ++j) {
      int i0 = k0 + 16 * j, i1 = i0 + 4, i2 = i0 + 8, i3 = i0 + 12;
      int c0 = csr[min(i0, last)];
      int c1 = csr[min(i1, last)];
      int c2 = csr[min(i2, last)];
      int c3 = csr[min(i3, last)];
      uint2 u0 = *(const uint2*)(hs + (long long)c0 * FH + i * 4);
      uint2 u1 = *(const uint2*)(hs + (long long)c1 * FH + i * 4);
      uint2 u2 = *(const uint2*)(hs + (long long)c2 * FH + i * 4);
      uint2 u3 = *(const uint2*)(hs + (long long)c3 * FH + i * 4);
      bool k0ok = i0 <= last, k1ok = i1 <= last, k2ok = i2 <= last, k3ok = i3 <= last;
      ax += (k0ok ? bflo(u0.x) : 0.0f) + (k1ok ? bflo(u1.x) : 0.0f) +
            (k2ok ? bflo(u2.x) : 0.0f) + (k3ok ? bflo(u3.x) : 0.0f);
      ay += (k0ok ? bfhi(u0.x) : 0.0f) + (k1ok ? bfhi(u1.x) : 0.0f) +
            (k2ok ? bfhi(u2.x) : 0.0f) + (k3ok ? bfhi(u3.x) : 0.0f);
      az += (k0ok ? bflo(u0.y) : 0.0f) + (k1ok ? bflo(u1.y) : 0.0f) +
            (k2ok ? bflo(u2.y) : 0.0f) + (k3ok ? bflo(u3.y) : 0.0f);
      aw += (k0ok ? bfhi(u0.y) : 0.0f) + (k1ok ? bfhi(u1.y) : 0.0f) +
            (k2ok ? bfhi(u2.y) : 0.0f) + (k3ok ? bfhi(u3.y) : 0.0f);
    }
    // reduce across the 4 groups (lane bits 4,5) — butterfly, all lanes get sum
    ax += __shfl_xor(ax, 16); ax += __shfl_xor(ax, 32);
    ay += __shfl_xor(ay, 16); ay += __shfl_xor(ay, 32);
    az += __shfl_xor(az, 16); az += __shfl_xor(az, 32);
    aw += __shfl_xor(aw, 16); aw += __shfl_xor(aw, 32);
    float dd = dis[d];
    float ox = ax * dd, oy = ay * dd, oz = az * dd, ow = aw * dd;
    if (g == 0) {
      float4 o4 = {ox, oy, oz, ow};
      *(float4*)(out + (long long)d * FH + i * 4) = o4;
    }
    s1x += ox; s2x += ox * ox;
    s1y += oy; s2y += oy * oy;
    s1z += oz; s2z += oz * oz;
    s1w += ow; s2w += ow * ow;
  }
  if (g == 0) {  // group-0 lanes hold one copy of the per-feature sums
    atomicAdd(&ls[i * 4 + 0], s1x);
    atomicAdd(&ls[i * 4 + 1], s1y);
    atomicAdd(&ls[i * 4 + 2], s1z);
    atomicAdd(&ls[i * 4 + 3], s1w);
    atomicAdd(&ls[FH + i * 4 + 0], s2x);
    atomicAdd(&ls[FH + i * 4 + 1], s2y);
    atomicAdd(&ls[FH + i * 4 + 2], s2z);
    atomicAdd(&ls[FH + i * 4 + 3], s2w);
  }
  __syncthreads();
  if (tid < 2 * FH) atomicAdd(&stats[tid], ls[tid]);
}

__global__ void k_bn_finalize(const float* __restrict__ stats, const float* __restrict__ gamma,
                              const float* __restrict__ beta, float* __restrict__ scsh) {
  int f = threadIdx.x;
  if (f < FH) {
    float mean = stats[f] * (1.0f / NNODES);
    float var = stats[FH + f] * (1.0f / NNODES) - mean * mean;
    float s = gamma[f] * rsqrtf(var + EPSV);
    scsh[f] = s;
    scsh[FH + f] = beta[f] - mean * s;  // bias b cancels in training-mode BN
  }
}

// ---------------- pooling (applies BN2+ReLU on load) ----------------

#define POOL_WAVES 1024

__global__ void k_pool(const float* __restrict__ h, const int* __restrict__ batch,
                       const float* __restrict__ scsh, float* __restrict__ pooled,
                       float* __restrict__ cnt) {
  const int CHUNK = (NNODES + POOL_WAVES - 1) / POOL_WAVES;
  int lane = threadIdx.x & 63;
  int wid = (blockIdx.x * blockDim.x + threadIdx.x) >> 6;
  int start = wid * CHUNK;
  if (start >= NNODES) return;
  int end = min(start + CHUNK, NNODES);
  float sc = scsh[lane], sh = scsh[FH + lane];
  int cur = batch[start];  // wave-uniform
  float acc = 0.0f;
  int cl = 0;
  for (int n = start; n < end; ++n) {
    int g = batch[n];
    if (g != cur) {  // uniform branch
      atomicAdd(&pooled[cur * FH + lane], acc);
      if (lane == 0) atomicAdd(&cnt[cur], (float)cl);
      acc = 0.0f;
      cl = 0;
      cur = g;
    }
    float v = fmaf(h[(long long)n * FH + lane], sc, sh);
    acc += fmaxf(v, 0.0f);
    ++cl;
  }
  atomicAdd(&pooled[cur * FH + lane], acc);
  if (lane == 0) atomicAdd(&cnt[cur], (float)cl);
}

// ---------------- final linear: out[G x 32] = (pooled/cnt) @ linW + linb -----

__global__ void k_final(const float* __restrict__ pooled, const float* __restrict__ cnt,
                        const float* __restrict__ linW, const float* __restrict__ linb,
                        float* __restrict__ out) {
  int t = blockIdx.x * blockDim.x + threadIdx.x;
  if (t >= NGRAPH * FOUT) return;
  int g = t / FOUT, o = t % FOUT;
  float inv = 1.0f / fmaxf(cnt[g], 1.0f);
  float acc = linb[o];
#pragma unroll
  for (int k = 0; k < FH; ++k) acc = fmaf(pooled[g * FH + k] * inv, linW[k * FOUT + o], acc);
  out[t] = acc;
}

extern "C" void kernel_launch(void* const* d_in, const int* in_sizes, int n_in,
                              void* d_out, int out_size, void* d_ws, size_t ws_size,
                              hipStream_t stream) {
  const float* x = (const float*)d_in[0];
  const int* edge_index = (const int*)d_in[1];
  const int* batch = (const int*)d_in[2];
  const float* W1 = (const float*)d_in[3];
  // d_in[4] = b1 (cancels in BN), d_in[6] = b2 (cancels in BN)
  const float* W2 = (const float*)d_in[5];
  const float* gamma = (const float*)d_in[7];
  const float* beta = (const float*)d_in[8];
  const float* linW = (const float*)d_in[9];
  const float* linb = (const float*)d_in[10];
  float* out = (float*)d_out;

  const int* esrc = edge_index;           // edge_index[0, :]
  const int* edst = edge_index + NEDGES;  // edge_index[1, :]

  // workspace layout (bufA region kept float-sized; used as bf16)
  ushort_t* bufA = (ushort_t*)d_ws;                        // N*64 bf16 (GEMM out, dis-scaled)
  float* bufB = (float*)d_ws + (long long)NNODES * FH;     // N*64 fp32 (aggregation output)
  float* dis = bufB + (long long)NNODES * FH;              // N
  int* off = (int*)(dis + NNODES);                         // N+1
  int* csr = off + (NNODES + 1);                           // E
  int* bsum = csr + NEDGES;                                // NBLK
  int* boff = bsum + NBLK;                                 // NBLK
  int* cursor = boff + NBLK;                               // N   --- zeroed region start
  float* stats1 = (float*)(cursor + NNODES);               // 128
  float* scsh1 = stats1 + 2 * FH;                          // 128
  float* stats2 = scsh1 + 2 * FH;                          // 128
  float* scsh2 = stats2 + 2 * FH;                          // 128
  float* pooled = scsh2 + 2 * FH;                          // G*64
  float* cnt = pooled + NGRAPH * FH;                       // G   --- zeroed region end

  const int BT = 256;
  const int gN = (NNODES + BT - 1) / BT;
  const int gE = (NEDGES + BT - 1) / BT;
  const int gW = (NNODES * 64 + BT - 1) / BT;  // one wave per row

  // zero cursor + stats + pooled + cnt in one shot (contiguous)
  hipMemsetAsync(cursor, 0,
                 (size_t)(NNODES + 4 * 2 * FH + NGRAPH * FH + NGRAPH) * sizeof(float), stream);

  // degrees (raw), CSR offsets, then rsqrt in place, then XCD-partitioned fill
  k_init_deg<<<gN, BT, 0, stream>>>(dis);
  k_deg_accum<<<gE, BT, 0, stream>>>(edst, dis);
  k_blocksum<<<NBLK, SCAN_BT, 0, stream>>>(dis, bsum);
  k_scan_bsums<<<1, 512, 0, stream>>>(bsum, boff);
  k_scan_final<<<NBLK, SCAN_BT, 0, stream>>>(dis, boff, off);
  k_rsqrt<<<gN, BT, 0, stream>>>(dis);
  k_fill<<<2048, BT, 0, stream>>>(esrc, edst, off, cursor, csr);

  // layer 1
  k_gemm<FIN, false><<<gW, BT, 0, stream>>>(x, W1, nullptr, nullptr, dis, bufA);
  k_gather<<<2048, BT, 0, stream>>>(bufA, csr, off, dis, bufB, stats1);
  k_bn_finalize<<<1, 64, 0, stream>>>(stats1, gamma, beta, scsh1);

  // layer 2 (BN1+ReLU fused into GEMM input load)
  k_gemm<FH, true><<<gW, BT, 0, stream>>>(bufB, W2, scsh1, scsh1 + FH, dis, bufA);
  k_gather<<<2048, BT, 0, stream>>>(bufA, csr, off, dis, bufB, stats2);
  k_bn_finalize<<<1, 64, 0, stream>>>(stats2, gamma, beta, scsh2);

  // pooling (BN2+ReLU fused) + final linear
  k_pool<<<POOL_WAVES * 64 / BT, BT, 0, stream>>>(bufB, batch, scsh2, pooled, cnt);
  k_final<<<(NGRAPH * FOUT + BT - 1) / BT, BT, 0, stream>>>(pooled, cnt, linW, linb, out);
}

// Round 9
// 445.886 us; speedup vs baseline: 1.5384x; 1.5384x over previous
//
#include <hip/hip_runtime.h>

#define NNODES 100000
#define NEDGES 1600000
#define FIN 128
#define FH 64
#define FOUT 32
#define NGRAPH 128
#define EPSV 1e-5f

#define SCAN_BT 256
#define NBLK ((NNODES + SCAN_BT - 1) / SCAN_BT)  // 391

typedef unsigned short ushort_t;
typedef __attribute__((ext_vector_type(8))) short bf16x8;
typedef __attribute__((ext_vector_type(4))) float f32x4;

// ---- bf16 helpers (RNE) ----
__device__ inline unsigned f2bf(float f) {
  union { float f; unsigned u; } x;
  x.f = f;
  return (x.u + 0x7fffu + ((x.u >> 16) & 1u)) >> 16;
}
__device__ inline float bflo(unsigned u) {
  union { unsigned u; float f; } x;
  x.u = u << 16;
  return x.f;
}
__device__ inline float bfhi(unsigned u) {
  union { unsigned u; float f; } x;
  x.u = u & 0xffff0000u;
  return x.f;
}

// ---------------- degree / normalization ----------------

__global__ void k_init_deg(float* __restrict__ deg) {
  int i = blockIdx.x * blockDim.x + threadIdx.x;
  if (i < NNODES) deg[i] = 1.0f;  // self-loop contributes 1
}

__global__ void k_deg_accum(const int* __restrict__ dst, float* __restrict__ deg) {
  int i = blockIdx.x * blockDim.x + threadIdx.x;
  if (i < NEDGES) atomicAdd(&deg[dst[i]], 1.0f);
}

__global__ void k_rsqrt(float* __restrict__ deg) {
  int i = blockIdx.x * blockDim.x + threadIdx.x;
  if (i < NNODES) deg[i] = rsqrtf(deg[i]);  // deg >= 1 always
}

// ---------------- CSR build: hierarchical exclusive scan of in-degrees ------

__global__ void k_blocksum(const float* __restrict__ deg, int* __restrict__ bsum) {
  __shared__ int ls[SCAN_BT];
  int b = blockIdx.x, t = threadIdx.x;
  int i = b * SCAN_BT + t;
  ls[t] = (i < NNODES) ? (int)deg[i] - 1 : 0;
  __syncthreads();
  for (int s = SCAN_BT / 2; s > 0; s >>= 1) {
    if (t < s) ls[t] += ls[t + s];
    __syncthreads();
  }
  if (t == 0) bsum[b] = ls[0];
}

__global__ void k_scan_bsums(const int* __restrict__ bsum, int* __restrict__ boff) {
  __shared__ int ls[512];
  int t = threadIdx.x;
  int v = (t < NBLK) ? bsum[t] : 0;
  ls[t] = v;
  __syncthreads();
  for (int s = 1; s < 512; s <<= 1) {
    int add = (t >= s) ? ls[t - s] : 0;
    __syncthreads();
    ls[t] += add;
    __syncthreads();
  }
  if (t < NBLK) boff[t] = ls[t] - v;  // exclusive
}

__global__ void k_scan_final(const float* __restrict__ deg, const int* __restrict__ boff,
                             int* __restrict__ off) {
  __shared__ int ls[SCAN_BT];
  int b = blockIdx.x, t = threadIdx.x;
  int i = b * SCAN_BT + t;
  int v = (i < NNODES) ? (int)deg[i] - 1 : 0;
  ls[t] = v;
  __syncthreads();
  for (int s = 1; s < SCAN_BT; s <<= 1) {
    int add = (t >= s) ? ls[t - s] : 0;
    __syncthreads();
    ls[t] += add;
    __syncthreads();
  }
  if (i < NNODES) off[i] = boff[b] + ls[t] - v;  // exclusive offset
  if (i == NNODES - 1) off[NNODES] = boff[b] + ls[t];
}

// XCD-partitioned fill: blocks of class (blockIdx&7) handle only dst in their
// 12500-node slice -> each csr line / cursor counter is owned by ONE XCD's L2.

__global__ void k_fill(const int* __restrict__ src, const int* __restrict__ dst,
                       const int* __restrict__ off, int* __restrict__ cursor,
                       int* __restrict__ csr) {
  const int SLICE = NNODES / 8;  // 12500
  int xcd = blockIdx.x & 7;
  int lo = xcd * SLICE, hi = lo + SLICE;
  int chunk = blockIdx.x >> 3;
  int nchunk = gridDim.x >> 3;
  for (int i = chunk * blockDim.x + threadIdx.x; i < NEDGES; i += nchunk * blockDim.x) {
    int d = dst[i];
    if (d >= lo && d < hi) {
      int p = atomicAdd(&cursor[d], 1);
      csr[off[d] + p] = src[i];
    }
  }
}

// ---------------- MFMA GEMM: out[N x 64] = act(A[N x K]) @ W[K x 64] --------
// 4 waves/block, wave = 16 rows x 64 cols (4 col-tile accumulators), K
// unrolled in 32-steps (16x16x32 bf16 MFMA). W converted to bf16 and
// TRANSPOSED into LDS (Wt[col][k], padded stride K+8) so a B-fragment is one
// aligned ds_read_b128. A-frags: 2 dwordx4 per k-step per lane, BN+ReLU fused
// (layer 2), converted to bf16 in-register. Epilogue scales by dis[row],
// stores bf16. Frag layout: A row=lane&15, k=8*(lane>>4)+j; B col=lane&15,
// same k; D col=lane&15, row=4*(lane>>4)+r (verified m89 convention).

template <int K, bool BN>
__global__ void k_gemm_mfma(const float* __restrict__ A, const float* __restrict__ W,
                            const float* __restrict__ scsh, const float* __restrict__ dis,
                            ushort_t* __restrict__ out) {
  const int WT = K + 8;  // padded k-stride (136 or 72): 16B-aligned rows, spread banks
  __shared__ ushort_t wt[64 * (K + 8)];
  // stage W -> bf16, transposed: wt[col*WT + k]
  for (int idx = threadIdx.x; idx < K * 64; idx += 256) {
    int k = idx >> 6, col = idx & 63;
    wt[col * WT + k] = (ushort_t)f2bf(W[idx]);
  }
  __syncthreads();

  int wave = threadIdx.x >> 6;
  int lane = threadIdx.x & 63;
  int rrow = lane & 15;  // A-row within tile / output col within tile
  int g = lane >> 4;     // k-subgroup
  int row0 = (blockIdx.x * 4 + wave) * 16;
  int arow = min(row0 + rrow, NNODES - 1);  // clamp (loads stay valid)
  const float* a = A + (long long)arow * K;

  f32x4 acc0 = {0.f, 0.f, 0.f, 0.f}, acc1 = acc0, acc2 = acc0, acc3 = acc0;

#pragma unroll
  for (int ks = 0; ks < K / 32; ++ks) {
    int koff = ks * 32 + g * 8;
    float4 xa = *(const float4*)(a + koff);
    float4 xb = *(const float4*)(a + koff + 4);
    float xs[8] = {xa.x, xa.y, xa.z, xa.w, xb.x, xb.y, xb.z, xb.w};
    if (BN) {
#pragma unroll
      for (int j = 0; j < 8; ++j)
        xs[j] = fmaxf(fmaf(xs[j], scsh[koff + j], scsh[K + koff + j]), 0.0f);
    }
    bf16x8 af;
#pragma unroll
    for (int j = 0; j < 8; ++j) af[j] = (short)f2bf(xs[j]);
    bf16x8 b0 = *(const bf16x8*)&wt[(0 * 16 + rrow) * WT + koff];
    bf16x8 b1 = *(const bf16x8*)&wt[(1 * 16 + rrow) * WT + koff];
    bf16x8 b2 = *(const bf16x8*)&wt[(2 * 16 + rrow) * WT + koff];
    bf16x8 b3 = *(const bf16x8*)&wt[(3 * 16 + rrow) * WT + koff];
    acc0 = __builtin_amdgcn_mfma_f32_16x16x32_bf16(af, b0, acc0, 0, 0, 0);
    acc1 = __builtin_amdgcn_mfma_f32_16x16x32_bf16(af, b1, acc1, 0, 0, 0);
    acc2 = __builtin_amdgcn_mfma_f32_16x16x32_bf16(af, b2, acc2, 0, 0, 0);
    acc3 = __builtin_amdgcn_mfma_f32_16x16x32_bf16(af, b3, acc3, 0, 0, 0);
  }

  // epilogue: D[r][col] with row = row0 + 4*g + r, col = ct*16 + rrow
  int orow0 = row0 + g * 4;
#pragma unroll
  for (int r = 0; r < 4; ++r) {
    int orow = orow0 + r;
    if (orow < NNODES) {
      float d = dis[orow];
      ushort_t* o = out + (long long)orow * FH + rrow;
      o[0] = (ushort_t)f2bf(acc0[r] * d);
      o[16] = (ushort_t)f2bf(acc1[r] * d);
      o[32] = (ushort_t)f2bf(acc2[r] * d);
      o[48] = (ushort_t)f2bf(acc3[r] * d);
    }
  }
}

// ---------------- aggregation: out[d] = dis[d] * (hs[d] + sum hs[csr]) ------
// hs is bf16 (128B rows). Wave = 4 groups x 16 lanes; each lane loads uint2
// (4 bf16 feats). 4 independent row chains per group per iteration (16
// edges/iter/wave). Uniform trip count, tails via clamp+select. fp32 accum.

__global__ void k_gather(const ushort_t* __restrict__ hs, const int* __restrict__ csr,
                         const int* __restrict__ off, const float* __restrict__ dis,
                         float* __restrict__ out, float* __restrict__ stats) {
  __shared__ float ls[2 * FH];
  int tid = threadIdx.x;
  if (tid < 2 * FH) ls[tid] = 0.0f;
  __syncthreads();
  int lane = tid & 63;
  int g = lane >> 4;  // neighbor group 0..3
  int i = lane & 15;  // feature-quad: features [4i, 4i+3]
  int wid = (blockIdx.x * blockDim.x + tid) >> 6;
  int nw = (gridDim.x * blockDim.x) >> 6;
  float s1x = 0, s1y = 0, s1z = 0, s1w = 0;
  float s2x = 0, s2y = 0, s2z = 0, s2w = 0;
  for (int d = wid; d < NNODES; d += nw) {
    int b = off[d], e = off[d + 1];
    uint2 su = *(const uint2*)(hs + (long long)d * FH + i * 4);
    float ax = (g == 0) ? bflo(su.x) : 0.0f;
    float ay = (g == 0) ? bfhi(su.x) : 0.0f;
    float az = (g == 0) ? bflo(su.y) : 0.0f;
    float aw = (g == 0) ? bfhi(su.y) : 0.0f;
    int niter = (e - b + 15) >> 4;  // wave-uniform
    int last = e - 1;
    int k0 = b + g;
    for (int j = 0; j < niter; ++j) {
      int i0 = k0 + 16 * j, i1 = i0 + 4, i2 = i0 + 8, i3 = i0 + 12;
      int c0 = csr[min(i0, last)];
      int c1 = csr[min(i1, last)];
      int c2 = csr[min(i2, last)];
      int c3 = csr[min(i3, last)];
      uint2 u0 = *(const uint2*)(hs + (long long)c0 * FH + i * 4);
      uint2 u1 = *(const uint2*)(hs + (long long)c1 * FH + i * 4);
      uint2 u2 = *(const uint2*)(hs + (long long)c2 * FH + i * 4);
      uint2 u3 = *(const uint2*)(hs + (long long)c3 * FH + i * 4);
      bool k0ok = i0 <= last, k1ok = i1 <= last, k2ok = i2 <= last, k3ok = i3 <= last;
      ax += (k0ok ? bflo(u0.x) : 0.0f) + (k1ok ? bflo(u1.x) : 0.0f) +
            (k2ok ? bflo(u2.x) : 0.0f) + (k3ok ? bflo(u3.x) : 0.0f);
      ay += (k0ok ? bfhi(u0.x) : 0.0f) + (k1ok ? bfhi(u1.x) : 0.0f) +
            (k2ok ? bfhi(u2.x) : 0.0f) + (k3ok ? bfhi(u3.x) : 0.0f);
      az += (k0ok ? bflo(u0.y) : 0.0f) + (k1ok ? bflo(u1.y) : 0.0f) +
            (k2ok ? bflo(u2.y) : 0.0f) + (k3ok ? bflo(u3.y) : 0.0f);
      aw += (k0ok ? bfhi(u0.y) : 0.0f) + (k1ok ? bfhi(u1.y) : 0.0f) +
            (k2ok ? bfhi(u2.y) : 0.0f) + (k3ok ? bfhi(u3.y) : 0.0f);
    }
    // reduce across the 4 groups (lane bits 4,5) — butterfly, all lanes get sum
    ax += __shfl_xor(ax, 16); ax += __shfl_xor(ax, 32);
    ay += __shfl_xor(ay, 16); ay += __shfl_xor(ay, 32);
    az += __shfl_xor(az, 16); az += __shfl_xor(az, 32);
    aw += __shfl_xor(aw, 16); aw += __shfl_xor(aw, 32);
    float dd = dis[d];
    float ox = ax * dd, oy = ay * dd, oz = az * dd, ow = aw * dd;
    if (g == 0) {
      float4 o4 = {ox, oy, oz, ow};
      *(float4*)(out + (long long)d * FH + i * 4) = o4;
    }
    s1x += ox; s2x += ox * ox;
    s1y += oy; s2y += oy * oy;
    s1z += oz; s2z += oz * oz;
    s1w += ow; s2w += ow * ow;
  }
  if (g == 0) {  // group-0 lanes hold one copy of the per-feature sums
    atomicAdd(&ls[i * 4 + 0], s1x);
    atomicAdd(&ls[i * 4 + 1], s1y);
    atomicAdd(&ls[i * 4 + 2], s1z);
    atomicAdd(&ls[i * 4 + 3], s1w);
    atomicAdd(&ls[FH + i * 4 + 0], s2x);
    atomicAdd(&ls[FH + i * 4 + 1], s2y);
    atomicAdd(&ls[FH + i * 4 + 2], s2z);
    atomicAdd(&ls[FH + i * 4 + 3], s2w);
  }
  __syncthreads();
  if (tid < 2 * FH) atomicAdd(&stats[tid], ls[tid]);
}

__global__ void k_bn_finalize(const float* __restrict__ stats, const float* __restrict__ gamma,
                              const float* __restrict__ beta, float* __restrict__ scsh) {
  int f = threadIdx.x;
  if (f < FH) {
    float mean = stats[f] * (1.0f / NNODES);
    float var = stats[FH + f] * (1.0f / NNODES) - mean * mean;
    float s = gamma[f] * rsqrtf(var + EPSV);
    scsh[f] = s;
    scsh[FH + f] = beta[f] - mean * s;  // bias b cancels in training-mode BN
  }
}

// ---------------- pooling (applies BN2+ReLU on load) ----------------

#define POOL_WAVES 1024

__global__ void k_pool(const float* __restrict__ h, const int* __restrict__ batch,
                       const float* __restrict__ scsh, float* __restrict__ pooled,
                       float* __restrict__ cnt) {
  const int CHUNK = (NNODES + POOL_WAVES - 1) / POOL_WAVES;
  int lane = threadIdx.x & 63;
  int wid = (blockIdx.x * blockDim.x + threadIdx.x) >> 6;
  int start = wid * CHUNK;
  if (start >= NNODES) return;
  int end = min(start + CHUNK, NNODES);
  float sc = scsh[lane], sh = scsh[FH + lane];
  int cur = batch[start];  // wave-uniform
  float acc = 0.0f;
  int cl = 0;
  for (int n = start; n < end; ++n) {
    int g = batch[n];
    if (g != cur) {  // uniform branch
      atomicAdd(&pooled[cur * FH + lane], acc);
      if (lane == 0) atomicAdd(&cnt[cur], (float)cl);
      acc = 0.0f;
      cl = 0;
      cur = g;
    }
    float v = fmaf(h[(long long)n * FH + lane], sc, sh);
    acc += fmaxf(v, 0.0f);
    ++cl;
  }
  atomicAdd(&pooled[cur * FH + lane], acc);
  if (lane == 0) atomicAdd(&cnt[cur], (float)cl);
}

// ---------------- final linear: out[G x 32] = (pooled/cnt) @ linW + linb -----

__global__ void k_final(const float* __restrict__ pooled, const float* __restrict__ cnt,
                        const float* __restrict__ linW, const float* __restrict__ linb,
                        float* __restrict__ out) {
  int t = blockIdx.x * blockDim.x + threadIdx.x;
  if (t >= NGRAPH * FOUT) return;
  int g = t / FOUT, o = t % FOUT;
  float inv = 1.0f / fmaxf(cnt[g], 1.0f);
  float acc = linb[o];
#pragma unroll
  for (int k = 0; k < FH; ++k) acc = fmaf(pooled[g * FH + k] * inv, linW[k * FOUT + o], acc);
  out[t] = acc;
}

extern "C" void kernel_launch(void* const* d_in, const int* in_sizes, int n_in,
                              void* d_out, int out_size, void* d_ws, size_t ws_size,
                              hipStream_t stream) {
  const float* x = (const float*)d_in[0];
  const int* edge_index = (const int*)d_in[1];
  const int* batch = (const int*)d_in[2];
  const float* W1 = (const float*)d_in[3];
  // d_in[4] = b1 (cancels in BN), d_in[6] = b2 (cancels in BN)
  const float* W2 = (const float*)d_in[5];
  const float* gamma = (const float*)d_in[7];
  const float* beta = (const float*)d_in[8];
  const float* linW = (const float*)d_in[9];
  const float* linb = (const float*)d_in[10];
  float* out = (float*)d_out;

  const int* esrc = edge_index;           // edge_index[0, :]
  const int* edst = edge_index + NEDGES;  // edge_index[1, :]

  // workspace layout (bufA region kept float-sized; used as bf16)
  ushort_t* bufA = (ushort_t*)d_ws;                        // N*64 bf16 (GEMM out, dis-scaled)
  float* bufB = (float*)d_ws + (long long)NNODES * FH;     // N*64 fp32 (aggregation output)
  float* dis = bufB + (long long)NNODES * FH;              // N
  int* off = (int*)(dis + NNODES);                         // N+1
  int* csr = off + (NNODES + 1);                           // E
  int* bsum = csr + NEDGES;                                // NBLK
  int* boff = bsum + NBLK;                                 // NBLK
  int* cursor = boff + NBLK;                               // N   --- zeroed region start
  float* stats1 = (float*)(cursor + NNODES);               // 128
  float* scsh1 = stats1 + 2 * FH;                          // 128
  float* stats2 = scsh1 + 2 * FH;                          // 128
  float* scsh2 = stats2 + 2 * FH;                          // 128
  float* pooled = scsh2 + 2 * FH;                          // G*64
  float* cnt = pooled + NGRAPH * FH;                       // G   --- zeroed region end

  const int BT = 256;
  const int gN = (NNODES + BT - 1) / BT;
  const int gE = (NEDGES + BT - 1) / BT;
  const int gM = (NNODES + 63) / 64;  // MFMA gemm: 64 rows per block

  // zero cursor + stats + pooled + cnt in one shot (contiguous)
  hipMemsetAsync(cursor, 0,
                 (size_t)(NNODES + 4 * 2 * FH + NGRAPH * FH + NGRAPH) * sizeof(float), stream);

  // degrees (raw), CSR offsets, then rsqrt in place, then XCD-partitioned fill
  k_init_deg<<<gN, BT, 0, stream>>>(dis);
  k_deg_accum<<<gE, BT, 0, stream>>>(edst, dis);
  k_blocksum<<<NBLK, SCAN_BT, 0, stream>>>(dis, bsum);
  k_scan_bsums<<<1, 512, 0, stream>>>(bsum, boff);
  k_scan_final<<<NBLK, SCAN_BT, 0, stream>>>(dis, boff, off);
  k_rsqrt<<<gN, BT, 0, stream>>>(dis);
  k_fill<<<2048, BT, 0, stream>>>(esrc, edst, off, cursor, csr);

  // layer 1
  k_gemm_mfma<FIN, false><<<gM, BT, 0, stream>>>(x, W1, nullptr, dis, bufA);
  k_gather<<<2048, BT, 0, stream>>>(bufA, csr, off, dis, bufB, stats1);
  k_bn_finalize<<<1, 64, 0, stream>>>(stats1, gamma, beta, scsh1);

  // layer 2 (BN1+ReLU fused into GEMM input load)
  k_gemm_mfma<FH, true><<<gM, BT, 0, stream>>>(bufB, W2, scsh1, dis, bufA);
  k_gather<<<2048, BT, 0, stream>>>(bufA, csr, off, dis, bufB, stats2);
  k_bn_finalize<<<1, 64, 0, stream>>>(stats2, gamma, beta, scsh2);

  // pooling (BN2+ReLU fused) + final linear
  k_pool<<<POOL_WAVES * 64 / BT, BT, 0, stream>>>(bufB, batch, scsh2, pooled, cnt);
  k_final<<<(NGRAPH * FOUT + BT - 1) / BT, BT, 0, stream>>>(pooled, cnt, linW, linb, out);
}

// Round 10
// 418.301 us; speedup vs baseline: 1.6398x; 1.0659x over previous
//
#include <hip/hip_runtime.h>

#define NNODES 100000
#define NEDGES 1600000
#define FIN 128
#define FH 64
#define FOUT 32
#define NGRAPH 128
#define EPSV 1e-5f

#define SCAN_BT 256
#define NBLK ((NNODES + SCAN_BT - 1) / SCAN_BT)  // 391

typedef unsigned short ushort_t;
typedef __attribute__((ext_vector_type(8))) short bf16x8;
typedef __attribute__((ext_vector_type(4))) float f32x4;

// ---- bf16 helpers (RNE) ----
__device__ inline unsigned f2bf(float f) {
  union { float f; unsigned u; } x;
  x.f = f;
  return (x.u + 0x7fffu + ((x.u >> 16) & 1u)) >> 16;
}
__device__ inline float bflo(unsigned u) {
  union { unsigned u; float f; } x;
  x.u = u << 16;
  return x.f;
}
__device__ inline float bfhi(unsigned u) {
  union { unsigned u; float f; } x;
  x.u = u & 0xffff0000u;
  return x.f;
}

// ---------------- degree accumulation (deg zeroed by memset; self-loop
// folded in later as deg+1). XCD-partitioned: same L2-ownership trick as
// k_fill -> no cross-XCD atomic line ping-pong.

__global__ void k_deg_accum(const int* __restrict__ dst, int* __restrict__ deg) {
  const int SLICE = NNODES / 8;  // 12500
  int xcd = blockIdx.x & 7;
  int lo = xcd * SLICE, hi = lo + SLICE;
  int chunk = blockIdx.x >> 3;
  int nchunk = gridDim.x >> 3;
  for (int i = chunk * blockDim.x + threadIdx.x; i < NEDGES; i += nchunk * blockDim.x) {
    int d = dst[i];
    if (d >= lo && d < hi) atomicAdd(&deg[d], 1);
  }
}

// ---------------- CSR build: hierarchical exclusive scan of in-degrees ------

__global__ void k_blocksum(const int* __restrict__ deg, int* __restrict__ bsum) {
  __shared__ int ls[SCAN_BT];
  int b = blockIdx.x, t = threadIdx.x;
  int i = b * SCAN_BT + t;
  ls[t] = (i < NNODES) ? deg[i] : 0;
  __syncthreads();
  for (int s = SCAN_BT / 2; s > 0; s >>= 1) {
    if (t < s) ls[t] += ls[t + s];
    __syncthreads();
  }
  if (t == 0) bsum[b] = ls[0];
}

__global__ void k_scan_bsums(const int* __restrict__ bsum, int* __restrict__ boff) {
  __shared__ int ls[512];
  int t = threadIdx.x;
  int v = (t < NBLK) ? bsum[t] : 0;
  ls[t] = v;
  __syncthreads();
  for (int s = 1; s < 512; s <<= 1) {
    int add = (t >= s) ? ls[t - s] : 0;
    __syncthreads();
    ls[t] += add;
    __syncthreads();
  }
  if (t < NBLK) boff[t] = ls[t] - v;  // exclusive
}

// exclusive offsets + fused dis = rsqrt(deg+1) (self-loop included in norm)

__global__ void k_scan_final(const int* __restrict__ deg, const int* __restrict__ boff,
                             int* __restrict__ off, float* __restrict__ dis) {
  __shared__ int ls[SCAN_BT];
  int b = blockIdx.x, t = threadIdx.x;
  int i = b * SCAN_BT + t;
  int v = (i < NNODES) ? deg[i] : 0;
  ls[t] = v;
  __syncthreads();
  for (int s = 1; s < SCAN_BT; s <<= 1) {
    int add = (t >= s) ? ls[t - s] : 0;
    __syncthreads();
    ls[t] += add;
    __syncthreads();
  }
  if (i < NNODES) {
    off[i] = boff[b] + ls[t] - v;  // exclusive offset
    dis[i] = rsqrtf((float)v + 1.0f);
  }
  if (i == NNODES - 1) off[NNODES] = boff[b] + ls[t];
}

// XCD-partitioned fill (csr/cursor lines owned by one XCD's L2)

__global__ void k_fill(const int* __restrict__ src, const int* __restrict__ dst,
                       const int* __restrict__ off, int* __restrict__ cursor,
                       int* __restrict__ csr) {
  const int SLICE = NNODES / 8;  // 12500
  int xcd = blockIdx.x & 7;
  int lo = xcd * SLICE, hi = lo + SLICE;
  int chunk = blockIdx.x >> 3;
  int nchunk = gridDim.x >> 3;
  for (int i = chunk * blockDim.x + threadIdx.x; i < NEDGES; i += nchunk * blockDim.x) {
    int d = dst[i];
    if (d >= lo && d < hi) {
      int p = atomicAdd(&cursor[d], 1);
      csr[off[d] + p] = src[i];
    }
  }
}

// ---------------- MFMA GEMM: out[N x 64] = act(A[N x K]) @ W[K x 64] --------
// 4 waves/block, wave = 16 rows x 64 cols, 16x16x32 bf16 MFMA, W transposed
// into LDS. BN=true: sc/sh computed from raw stats in the prologue (bn_finalize
// fused away). Epilogue scales by dis[row], stores bf16.

template <int K, bool BN>
__global__ void k_gemm_mfma(const float* __restrict__ A, const float* __restrict__ W,
                            const float* __restrict__ stats, const float* __restrict__ gamma,
                            const float* __restrict__ beta, const float* __restrict__ dis,
                            ushort_t* __restrict__ out) {
  const int WT = K + 8;
  __shared__ ushort_t wt[64 * (K + 8)];
  __shared__ float bn_sc[K], bn_sh[K];
  if (BN && threadIdx.x < K) {
    int f = threadIdx.x;
    float mean = stats[f] * (1.0f / NNODES);
    float var = stats[K + f] * (1.0f / NNODES) - mean * mean;
    float s = gamma[f] * rsqrtf(var + EPSV);
    bn_sc[f] = s;
    bn_sh[f] = beta[f] - mean * s;  // bias b cancels in training-mode BN
  }
  for (int idx = threadIdx.x; idx < K * 64; idx += 256) {
    int k = idx >> 6, col = idx & 63;
    wt[col * WT + k] = (ushort_t)f2bf(W[idx]);
  }
  __syncthreads();

  int wave = threadIdx.x >> 6;
  int lane = threadIdx.x & 63;
  int rrow = lane & 15;
  int g = lane >> 4;
  int row0 = (blockIdx.x * 4 + wave) * 16;
  int arow = min(row0 + rrow, NNODES - 1);
  const float* a = A + (long long)arow * K;

  f32x4 acc0 = {0.f, 0.f, 0.f, 0.f}, acc1 = acc0, acc2 = acc0, acc3 = acc0;

#pragma unroll
  for (int ks = 0; ks < K / 32; ++ks) {
    int koff = ks * 32 + g * 8;
    float4 xa = *(const float4*)(a + koff);
    float4 xb = *(const float4*)(a + koff + 4);
    float xs[8] = {xa.x, xa.y, xa.z, xa.w, xb.x, xb.y, xb.z, xb.w};
    if (BN) {
#pragma unroll
      for (int j = 0; j < 8; ++j)
        xs[j] = fmaxf(fmaf(xs[j], bn_sc[koff + j], bn_sh[koff + j]), 0.0f);
    }
    bf16x8 af;
#pragma unroll
    for (int j = 0; j < 8; ++j) af[j] = (short)f2bf(xs[j]);
    bf16x8 b0 = *(const bf16x8*)&wt[(0 * 16 + rrow) * WT + koff];
    bf16x8 b1 = *(const bf16x8*)&wt[(1 * 16 + rrow) * WT + koff];
    bf16x8 b2 = *(const bf16x8*)&wt[(2 * 16 + rrow) * WT + koff];
    bf16x8 b3 = *(const bf16x8*)&wt[(3 * 16 + rrow) * WT + koff];
    acc0 = __builtin_amdgcn_mfma_f32_16x16x32_bf16(af, b0, acc0, 0, 0, 0);
    acc1 = __builtin_amdgcn_mfma_f32_16x16x32_bf16(af, b1, acc1, 0, 0, 0);
    acc2 = __builtin_amdgcn_mfma_f32_16x16x32_bf16(af, b2, acc2, 0, 0, 0);
    acc3 = __builtin_amdgcn_mfma_f32_16x16x32_bf16(af, b3, acc3, 0, 0, 0);
  }

  int orow0 = row0 + g * 4;
#pragma unroll
  for (int r = 0; r < 4; ++r) {
    int orow = orow0 + r;
    if (orow < NNODES) {
      float d = dis[orow];
      ushort_t* o = out + (long long)orow * FH + rrow;
      o[0] = (ushort_t)f2bf(acc0[r] * d);
      o[16] = (ushort_t)f2bf(acc1[r] * d);
      o[32] = (ushort_t)f2bf(acc2[r] * d);
      o[48] = (ushort_t)f2bf(acc3[r] * d);
    }
  }
}

// ---------------- aggregation: out[d] = dis[d] * (hs[d] + sum hs[csr]) ------
// TWO nodes per wave (dA=p, dB=p+N/2; N even -> perfect pairing): 8
// independent csr+row load chains per iteration (R4 evidence: chain count is
// the latency-hiding lever). 4 groups x 16 lanes, lane loads uint2 (4 bf16).
// Branchless: niter = max, clamp+select tails, last=max(e-1,0) guards empty.
// Group 0 stores A's row, group 1 stores B's. BN stats fused.

__global__ void k_gather(const ushort_t* __restrict__ hs, const int* __restrict__ csr,
                         const int* __restrict__ off, const float* __restrict__ dis,
                         float* __restrict__ out, float* __restrict__ stats) {
  __shared__ float ls[2 * FH];
  int tid = threadIdx.x;
  if (tid < 2 * FH) ls[tid] = 0.0f;
  __syncthreads();
  int lane = tid & 63;
  int g = lane >> 4;  // neighbor group 0..3
  int i = lane & 15;  // feature-quad: features [4i, 4i+3]
  int wid = (blockIdx.x * blockDim.x + tid) >> 6;
  int nw = (gridDim.x * blockDim.x) >> 6;
  const int HALF = NNODES / 2;
  float s1x = 0, s1y = 0, s1z = 0, s1w = 0;
  float s2x = 0, s2y = 0, s2z = 0, s2w = 0;
  for (int p = wid; p < HALF; p += nw) {
    int dA = p, dB = p + HALF;
    int bA = off[dA], eA = off[dA + 1];
    int bB = off[dB], eB = off[dB + 1];
    uint2 suA = *(const uint2*)(hs + (long long)dA * FH + i * 4);
    uint2 suB = *(const uint2*)(hs + (long long)dB * FH + i * 4);
    float axA = (g == 0) ? bflo(suA.x) : 0.0f;
    float ayA = (g == 0) ? bfhi(suA.x) : 0.0f;
    float azA = (g == 0) ? bflo(suA.y) : 0.0f;
    float awA = (g == 0) ? bfhi(suA.y) : 0.0f;
    float axB = (g == 0) ? bflo(suB.x) : 0.0f;
    float ayB = (g == 0) ? bfhi(suB.x) : 0.0f;
    float azB = (g == 0) ? bflo(suB.y) : 0.0f;
    float awB = (g == 0) ? bfhi(suB.y) : 0.0f;
    int nA = (eA - bA + 15) >> 4, nB = (eB - bB + 15) >> 4;
    int niter = max(nA, nB);  // wave-uniform
    int lastA = max(eA - 1, 0), lastB = max(eB - 1, 0);
    int kA = bA + g, kB = bB + g;
    for (int j = 0; j < niter; ++j) {
      int a0 = kA + 16 * j, a1 = a0 + 4, a2 = a0 + 8, a3 = a0 + 12;
      int b0 = kB + 16 * j, b1 = b0 + 4, b2 = b0 + 8, b3 = b0 + 12;
      int cA0 = csr[min(a0, lastA)];
      int cA1 = csr[min(a1, lastA)];
      int cA2 = csr[min(a2, lastA)];
      int cA3 = csr[min(a3, lastA)];
      int cB0 = csr[min(b0, lastB)];
      int cB1 = csr[min(b1, lastB)];
      int cB2 = csr[min(b2, lastB)];
      int cB3 = csr[min(b3, lastB)];
      uint2 uA0 = *(const uint2*)(hs + (long long)cA0 * FH + i * 4);
      uint2 uA1 = *(const uint2*)(hs + (long long)cA1 * FH + i * 4);
      uint2 uA2 = *(const uint2*)(hs + (long long)cA2 * FH + i * 4);
      uint2 uA3 = *(const uint2*)(hs + (long long)cA3 * FH + i * 4);
      uint2 uB0 = *(const uint2*)(hs + (long long)cB0 * FH + i * 4);
      uint2 uB1 = *(const uint2*)(hs + (long long)cB1 * FH + i * 4);
      uint2 uB2 = *(const uint2*)(hs + (long long)cB2 * FH + i * 4);
      uint2 uB3 = *(const uint2*)(hs + (long long)cB3 * FH + i * 4);
      bool A0 = a0 < eA, A1 = a1 < eA, A2 = a2 < eA, A3 = a3 < eA;
      bool B0 = b0 < eB, B1 = b1 < eB, B2 = b2 < eB, B3 = b3 < eB;
      axA += (A0 ? bflo(uA0.x) : 0.0f) + (A1 ? bflo(uA1.x) : 0.0f) +
             (A2 ? bflo(uA2.x) : 0.0f) + (A3 ? bflo(uA3.x) : 0.0f);
      ayA += (A0 ? bfhi(uA0.x) : 0.0f) + (A1 ? bfhi(uA1.x) : 0.0f) +
             (A2 ? bfhi(uA2.x) : 0.0f) + (A3 ? bfhi(uA3.x) : 0.0f);
      azA += (A0 ? bflo(uA0.y) : 0.0f) + (A1 ? bflo(uA1.y) : 0.0f) +
             (A2 ? bflo(uA2.y) : 0.0f) + (A3 ? bflo(uA3.y) : 0.0f);
      awA += (A0 ? bfhi(uA0.y) : 0.0f) + (A1 ? bfhi(uA1.y) : 0.0f) +
             (A2 ? bfhi(uA2.y) : 0.0f) + (A3 ? bfhi(uA3.y) : 0.0f);
      axB += (B0 ? bflo(uB0.x) : 0.0f) + (B1 ? bflo(uB1.x) : 0.0f) +
             (B2 ? bflo(uB2.x) : 0.0f) + (B3 ? bflo(uB3.x) : 0.0f);
      ayB += (B0 ? bfhi(uB0.x) : 0.0f) + (B1 ? bfhi(uB1.x) : 0.0f) +
             (B2 ? bfhi(uB2.x) : 0.0f) + (B3 ? bfhi(uB3.x) : 0.0f);
      azB += (B0 ? bflo(uB0.y) : 0.0f) + (B1 ? bflo(uB1.y) : 0.0f) +
             (B2 ? bflo(uB2.y) : 0.0f) + (B3 ? bflo(uB3.y) : 0.0f);
      awB += (B0 ? bfhi(uB0.y) : 0.0f) + (B1 ? bfhi(uB1.y) : 0.0f) +
             (B2 ? bfhi(uB2.y) : 0.0f) + (B3 ? bfhi(uB3.y) : 0.0f);
    }
    // butterfly across groups (lane bits 4,5)
    axA += __shfl_xor(axA, 16); axA += __shfl_xor(axA, 32);
    ayA += __shfl_xor(ayA, 16); ayA += __shfl_xor(ayA, 32);
    azA += __shfl_xor(azA, 16); azA += __shfl_xor(azA, 32);
    awA += __shfl_xor(awA, 16); awA += __shfl_xor(awA, 32);
    axB += __shfl_xor(axB, 16); axB += __shfl_xor(axB, 32);
    ayB += __shfl_xor(ayB, 16); ayB += __shfl_xor(ayB, 32);
    azB += __shfl_xor(azB, 16); azB += __shfl_xor(azB, 32);
    awB += __shfl_xor(awB, 16); awB += __shfl_xor(awB, 32);
    float ddA = dis[dA], ddB = dis[dB];
    float oxA = axA * ddA, oyA = ayA * ddA, ozA = azA * ddA, owA = awA * ddA;
    float oxB = axB * ddB, oyB = ayB * ddB, ozB = azB * ddB, owB = awB * ddB;
    if (g < 2) {  // group 0 stores A, group 1 stores B (parallel)
      int d = (g == 0) ? dA : dB;
      float4 o4;
      o4.x = (g == 0) ? oxA : oxB;
      o4.y = (g == 0) ? oyA : oyB;
      o4.z = (g == 0) ? ozA : ozB;
      o4.w = (g == 0) ? owA : owB;
      *(float4*)(out + (long long)d * FH + i * 4) = o4;
    }
    s1x += oxA + oxB; s2x += oxA * oxA + oxB * oxB;
    s1y += oyA + oyB; s2y += oyA * oyA + oyB * oyB;
    s1z += ozA + ozB; s2z += ozA * ozA + ozB * ozB;
    s1w += owA + owB; s2w += owA * owA + owB * owB;
  }
  if (g == 0) {
    atomicAdd(&ls[i * 4 + 0], s1x);
    atomicAdd(&ls[i * 4 + 1], s1y);
    atomicAdd(&ls[i * 4 + 2], s1z);
    atomicAdd(&ls[i * 4 + 3], s1w);
    atomicAdd(&ls[FH + i * 4 + 0], s2x);
    atomicAdd(&ls[FH + i * 4 + 1], s2y);
    atomicAdd(&ls[FH + i * 4 + 2], s2z);
    atomicAdd(&ls[FH + i * 4 + 3], s2w);
  }
  __syncthreads();
  if (tid < 2 * FH) atomicAdd(&stats[tid], ls[tid]);
}

// ---------------- pooling (BN2+ReLU fused; sc/sh computed per-lane) ---------

#define POOL_WAVES 1024

__global__ void k_pool(const float* __restrict__ h, const int* __restrict__ batch,
                       const float* __restrict__ stats, const float* __restrict__ gamma,
                       const float* __restrict__ beta, float* __restrict__ pooled,
                       float* __restrict__ cnt) {
  const int CHUNK = (NNODES + POOL_WAVES - 1) / POOL_WAVES;
  int lane = threadIdx.x & 63;
  int wid = (blockIdx.x * blockDim.x + threadIdx.x) >> 6;
  int start = wid * CHUNK;
  if (start >= NNODES) return;
  int end = min(start + CHUNK, NNODES);
  float mean = stats[lane] * (1.0f / NNODES);
  float var = stats[FH + lane] * (1.0f / NNODES) - mean * mean;
  float sc = gamma[lane] * rsqrtf(var + EPSV);
  float sh = beta[lane] - mean * sc;
  int cur = batch[start];  // wave-uniform
  float acc = 0.0f;
  int cl = 0;
  for (int n = start; n < end; ++n) {
    int g = batch[n];
    if (g != cur) {  // uniform branch
      atomicAdd(&pooled[cur * FH + lane], acc);
      if (lane == 0) atomicAdd(&cnt[cur], (float)cl);
      acc = 0.0f;
      cl = 0;
      cur = g;
    }
    float v = fmaf(h[(long long)n * FH + lane], sc, sh);
    acc += fmaxf(v, 0.0f);
    ++cl;
  }
  atomicAdd(&pooled[cur * FH + lane], acc);
  if (lane == 0) atomicAdd(&cnt[cur], (float)cl);
}

// ---------------- final linear: out[G x 32] = (pooled/cnt) @ linW + linb -----

__global__ void k_final(const float* __restrict__ pooled, const float* __restrict__ cnt,
                        const float* __restrict__ linW, const float* __restrict__ linb,
                        float* __restrict__ out) {
  int t = blockIdx.x * blockDim.x + threadIdx.x;
  if (t >= NGRAPH * FOUT) return;
  int g = t / FOUT, o = t % FOUT;
  float inv = 1.0f / fmaxf(cnt[g], 1.0f);
  float acc = linb[o];
#pragma unroll
  for (int k = 0; k < FH; ++k) acc = fmaf(pooled[g * FH + k] * inv, linW[k * FOUT + o], acc);
  out[t] = acc;
}

extern "C" void kernel_launch(void* const* d_in, const int* in_sizes, int n_in,
                              void* d_out, int out_size, void* d_ws, size_t ws_size,
                              hipStream_t stream) {
  const float* x = (const float*)d_in[0];
  const int* edge_index = (const int*)d_in[1];
  const int* batch = (const int*)d_in[2];
  const float* W1 = (const float*)d_in[3];
  // d_in[4] = b1 (cancels in BN), d_in[6] = b2 (cancels in BN)
  const float* W2 = (const float*)d_in[5];
  const float* gamma = (const float*)d_in[7];
  const float* beta = (const float*)d_in[8];
  const float* linW = (const float*)d_in[9];
  const float* linb = (const float*)d_in[10];
  float* out = (float*)d_out;

  const int* esrc = edge_index;           // edge_index[0, :]
  const int* edst = edge_index + NEDGES;  // edge_index[1, :]

  // workspace layout (bufA region float-sized; used as bf16)
  ushort_t* bufA = (ushort_t*)d_ws;                        // N*64 bf16 (GEMM out, dis-scaled)
  float* bufB = (float*)d_ws + (long long)NNODES * FH;     // N*64 fp32 (aggregation output)
  float* dis = bufB + (long long)NNODES * FH;              // N
  int* off = (int*)(dis + NNODES);                         // N+1
  int* csr = off + (NNODES + 1);                           // E
  int* bsum = csr + NEDGES;                                // NBLK
  int* boff = bsum + NBLK;                                 // NBLK
  int* deg = boff + NBLK;                                  // N   --- zeroed region start
  int* cursor = deg + NNODES;                              // N
  float* stats1 = (float*)(cursor + NNODES);               // 128
  float* stats2 = stats1 + 2 * FH;                         // 128
  float* pooled = stats2 + 2 * FH;                         // G*64
  float* cnt = pooled + NGRAPH * FH;                       // G   --- zeroed region end

  const int BT = 256;
  const int gN = (NNODES + BT - 1) / BT;
  const int gM = (NNODES + 63) / 64;  // MFMA gemm: 64 rows per block

  // zero deg + cursor + stats + pooled + cnt in one shot (contiguous)
  hipMemsetAsync(deg, 0,
                 (size_t)(2 * NNODES + 2 * 2 * FH + NGRAPH * FH + NGRAPH) * sizeof(int), stream);

  // degrees, CSR offsets + fused rsqrt, XCD-partitioned fill
  k_deg_accum<<<2048, BT, 0, stream>>>(edst, deg);
  k_blocksum<<<NBLK, SCAN_BT, 0, stream>>>(deg, bsum);
  k_scan_bsums<<<1, 512, 0, stream>>>(bsum, boff);
  k_scan_final<<<NBLK, SCAN_BT, 0, stream>>>(deg, boff, off, dis);
  k_fill<<<2048, BT, 0, stream>>>(esrc, edst, off, cursor, csr);

  // layer 1
  k_gemm_mfma<FIN, false><<<gM, BT, 0, stream>>>(x, W1, nullptr, nullptr, nullptr, dis, bufA);
  k_gather<<<2048, BT, 0, stream>>>(bufA, csr, off, dis, bufB, stats1);

  // layer 2 (BN1 finalize + apply + ReLU fused into GEMM)
  k_gemm_mfma<FH, true><<<gM, BT, 0, stream>>>(bufB, W2, stats1, gamma, beta, dis, bufA);
  k_gather<<<2048, BT, 0, stream>>>(bufA, csr, off, dis, bufB, stats2);

  // pooling (BN2 finalize + apply + ReLU fused) + final linear
  k_pool<<<POOL_WAVES * 64 / BT, BT, 0, stream>>>(bufB, batch, stats2, gamma, beta, pooled, cnt);
  k_final<<<(NGRAPH * FOUT + BT - 1) / BT, BT, 0, stream>>>(pooled, cnt, linW, linb, out);
}